// Round 1
// baseline (2570.640 us; speedup 1.0000x reference)
//
#include <hip/hip_runtime.h>

#define PP 8
#define ZD 16
#define H1C 128
#define H2C 512
#define CHC 224
#define NB 32768
#define EPSV 1e-5f

// header layout in d_ws (float offsets)
#define OFF_S1SUM 0
#define OFF_S1SQ  1024
#define OFF_SC1   2048
#define OFF_SH1   3072
#define OFF_S2SUM 4096
#define OFF_S2SQ  8192
#define OFF_SC2   12288
#define OFF_SH2   16384
#define HDR_BYTES 81920

// ---------------------------------------------------------------------------
// K1: BN1 stats. Computes h1 = z*W6^T + b6 on the fly (K=16), accumulates
// per-(p, feature) sum and sumsq partials, atomicAdd to header.
// grid (N/512, P), block 128 (one thread per h1 feature).
__global__ __launch_bounds__(128) void k1_stats1(
    const float* __restrict__ z, const float* __restrict__ W6,
    const float* __restrict__ b6, float* __restrict__ hdr) {
  __shared__ float zs[512 * ZD];      // 32 KB
  __shared__ float w6s[H1C * 17];     // padded stride 17
  const int t = threadIdx.x;
  const int p = blockIdx.y;
  const int n0 = blockIdx.x * 512;

  for (int i = t; i < H1C * ZD; i += 128) {
    int h = i >> 4, q = i & 15;
    w6s[h * 17 + q] = W6[(size_t)p * (H1C * ZD) + i];
  }
  for (int i = t; i < 512 * ZD; i += 128) zs[i] = z[(size_t)n0 * ZD + i];
  __syncthreads();

  float bb = b6[p * H1C + t];
  float s = 0.f, sq = 0.f;
  for (int n = 0; n < 512; ++n) {
    float v = bb;
#pragma unroll
    for (int q = 0; q < ZD; ++q) v = fmaf(zs[n * ZD + q], w6s[t * 17 + q], v);
    s += v;
    sq = fmaf(v, v, sq);
  }
  atomicAdd(&hdr[OFF_S1SUM + p * H1C + t], s);
  atomicAdd(&hdr[OFF_S1SQ + p * H1C + t], sq);
}

// K1b: finalize BN1 -> affine scale/shift
__global__ void k1_fin(const float* __restrict__ g6,
                       const float* __restrict__ be6, float* __restrict__ hdr) {
  int j = blockIdx.x * 256 + threadIdx.x;
  if (j >= PP * H1C) return;
  float mu = hdr[OFF_S1SUM + j] * (1.f / NB);
  float var = hdr[OFF_S1SQ + j] * (1.f / NB) - mu * mu;
  var = fmaxf(var, 0.f);
  float sc = g6[j] * rsqrtf(var + EPSV);
  hdr[OFF_SC1 + j] = sc;
  hdr[OFF_SH1 + j] = be6[j] - mu * sc;
}

// ---------------------------------------------------------------------------
// K2: GEMM2. Recomputes h1 tile from z (K=16), applies BN1 affine + ReLU into
// LDS, then 64x64 tile GEMM over K=128 (two 64-chunks). Writes h2_raw.
// grid (N/64, H2/64, pg), block 256, 4x4 outputs per thread.
__global__ __launch_bounds__(256) void k2_gemm2(
    const float* __restrict__ z, const float* __restrict__ W6,
    const float* __restrict__ b6, const float* __restrict__ W7,
    const float* __restrict__ b7, const float* __restrict__ hdr,
    float* __restrict__ h2buf, int p0) {
  __shared__ float zs[64 * ZD];
  __shared__ float w6s[H1C * 17];
  __shared__ float As[64 * 65];
  __shared__ float Bs[64 * 65];
  __shared__ float b6s[H1C], s1s[H1C], sh1s[H1C];
  const int t = threadIdx.x;
  const int pl = blockIdx.z, p = p0 + pl;
  const int n0 = blockIdx.x * 64;
  const int k0 = blockIdx.y * 64;

  for (int i = t; i < 64 * ZD; i += 256) zs[i] = z[(size_t)n0 * ZD + i];
  for (int i = t; i < H1C * ZD; i += 256) {
    int h = i >> 4, q = i & 15;
    w6s[h * 17 + q] = W6[(size_t)p * (H1C * ZD) + i];
  }
  if (t < H1C) {
    b6s[t] = b6[p * H1C + t];
    s1s[t] = hdr[OFF_SC1 + p * H1C + t];
    sh1s[t] = hdr[OFF_SH1 + p * H1C + t];
  }

  const int nr = t >> 4, kc = t & 15;
  float acc[4][4] = {{0.f, 0.f, 0.f, 0.f}};

  for (int hc = 0; hc < H1C; hc += 64) {
    __syncthreads();
    // stage A: compute h1 activation tile [64 n][64 h]
    for (int i = t; i < 4096; i += 256) {
      int n = i >> 6, hh = i & 63;
      int h = hc + hh;
      float v = b6s[h];
#pragma unroll
      for (int q = 0; q < ZD; ++q) v = fmaf(zs[n * ZD + q], w6s[h * 17 + q], v);
      v = fmaf(v, s1s[h], sh1s[h]);
      As[n * 65 + hh] = fmaxf(v, 0.f);
    }
    // stage B: W7 tile [64 k][64 h]
    for (int i = t; i < 4096; i += 256) {
      int kk = i >> 6, hh = i & 63;
      Bs[kk * 65 + hh] = W7[((size_t)p * H2C + k0 + kk) * H1C + hc + hh];
    }
    __syncthreads();
#pragma unroll 8
    for (int hh = 0; hh < 64; ++hh) {
      float a[4], b[4];
#pragma unroll
      for (int i = 0; i < 4; ++i) a[i] = As[(nr * 4 + i) * 65 + hh];
#pragma unroll
      for (int j = 0; j < 4; ++j) b[j] = Bs[(kc * 4 + j) * 65 + hh];
#pragma unroll
      for (int i = 0; i < 4; ++i)
#pragma unroll
        for (int j = 0; j < 4; ++j) acc[i][j] = fmaf(a[i], b[j], acc[i][j]);
    }
  }

#pragma unroll
  for (int i = 0; i < 4; ++i) {
    int n = n0 + nr * 4 + i;
    int k = k0 + kc * 4;
    float4 v;
    v.x = acc[i][0] + b7[p * H2C + k + 0];
    v.y = acc[i][1] + b7[p * H2C + k + 1];
    v.z = acc[i][2] + b7[p * H2C + k + 2];
    v.w = acc[i][3] + b7[p * H2C + k + 3];
    *(float4*)&h2buf[((size_t)pl * NB + n) * H2C + k] = v;
  }
}

// ---------------------------------------------------------------------------
// K3: BN2 stats over h2_raw. grid (N/1024, pg), block 256 (2 k cols each).
__global__ __launch_bounds__(256) void k3_stats2(
    const float* __restrict__ h2buf, float* __restrict__ hdr, int p0) {
  const int t = threadIdx.x;
  const int pl = blockIdx.y, p = p0 + pl;
  const int n0 = blockIdx.x * 1024;
  const float* base = h2buf + (size_t)pl * NB * H2C + (size_t)n0 * H2C;
  float s0 = 0.f, q0 = 0.f, s1 = 0.f, q1 = 0.f;
  for (int n = 0; n < 1024; ++n) {
    float v0 = base[(size_t)n * H2C + t];
    float v1 = base[(size_t)n * H2C + t + 256];
    s0 += v0;
    q0 = fmaf(v0, v0, q0);
    s1 += v1;
    q1 = fmaf(v1, v1, q1);
  }
  atomicAdd(&hdr[OFF_S2SUM + p * H2C + t], s0);
  atomicAdd(&hdr[OFF_S2SQ + p * H2C + t], q0);
  atomicAdd(&hdr[OFF_S2SUM + p * H2C + t + 256], s1);
  atomicAdd(&hdr[OFF_S2SQ + p * H2C + t + 256], q1);
}

__global__ void k3_fin(const float* __restrict__ g7,
                       const float* __restrict__ be7, float* __restrict__ hdr,
                       int p0, int pg) {
  int idx = blockIdx.x * 256 + threadIdx.x;
  if (idx >= pg * H2C) return;
  int row = p0 * H2C + idx;
  float mu = hdr[OFF_S2SUM + row] * (1.f / NB);
  float var = fmaxf(hdr[OFF_S2SQ + row] * (1.f / NB) - mu * mu, 0.f);
  float sc = g7[row] * rsqrtf(var + EPSV);
  hdr[OFF_SC2 + row] = sc;
  hdr[OFF_SH2 + row] = be7[row] - mu * sc;
}

// ---------------------------------------------------------------------------
// K4: GEMM3 (K=512) with BN2 affine + ReLU applied at A-staging, + b8,
// sigmoid, transposed store out[n][p][c].
// grid (N/64, ceil(C/64)=4, pg), block 256, 4x4 outputs per thread.
__global__ __launch_bounds__(256) void k4_gemm3(
    const float* __restrict__ h2buf, const float* __restrict__ W8,
    const float* __restrict__ b8, const float* __restrict__ hdr,
    float* __restrict__ out, int p0) {
  __shared__ float As[64 * 65];
  __shared__ float Bs[64 * 65];
  __shared__ float s2s[H2C], sh2s[H2C];
  const int t = threadIdx.x;
  const int pl = blockIdx.z, p = p0 + pl;
  const int n0 = blockIdx.x * 64;
  const int c0 = blockIdx.y * 64;

  for (int i = t; i < H2C; i += 256) {
    s2s[i] = hdr[OFF_SC2 + p * H2C + i];
    sh2s[i] = hdr[OFF_SH2 + p * H2C + i];
  }

  const int nr = t >> 4, cc = t & 15;
  float acc[4][4] = {{0.f, 0.f, 0.f, 0.f}};

  for (int kc0 = 0; kc0 < H2C; kc0 += 64) {
    __syncthreads();
    for (int i = t; i < 4096; i += 256) {
      int n = i >> 6, kk = i & 63;
      float v = h2buf[((size_t)pl * NB + n0 + n) * H2C + kc0 + kk];
      v = fmaf(v, s2s[kc0 + kk], sh2s[kc0 + kk]);
      As[n * 65 + kk] = fmaxf(v, 0.f);
    }
    for (int i = t; i < 4096; i += 256) {
      int c = i >> 6, kk = i & 63;
      float v = (c0 + c < CHC)
                    ? W8[((size_t)p * CHC + c0 + c) * H2C + kc0 + kk]
                    : 0.f;
      Bs[c * 65 + kk] = v;
    }
    __syncthreads();
#pragma unroll 8
    for (int kk = 0; kk < 64; ++kk) {
      float a[4], b[4];
#pragma unroll
      for (int i = 0; i < 4; ++i) a[i] = As[(nr * 4 + i) * 65 + kk];
#pragma unroll
      for (int j = 0; j < 4; ++j) b[j] = Bs[(cc * 4 + j) * 65 + kk];
#pragma unroll
      for (int i = 0; i < 4; ++i)
#pragma unroll
        for (int j = 0; j < 4; ++j) acc[i][j] = fmaf(a[i], b[j], acc[i][j]);
    }
  }

  const int cbase = c0 + cc * 4;
  if (cbase + 3 < CHC) {
#pragma unroll
    for (int i = 0; i < 4; ++i) {
      int n = n0 + nr * 4 + i;
      float4 v;
      float x0 = acc[i][0] + b8[p * CHC + cbase + 0];
      float x1 = acc[i][1] + b8[p * CHC + cbase + 1];
      float x2 = acc[i][2] + b8[p * CHC + cbase + 2];
      float x3 = acc[i][3] + b8[p * CHC + cbase + 3];
      v.x = 1.f / (1.f + __expf(-x0));
      v.y = 1.f / (1.f + __expf(-x1));
      v.z = 1.f / (1.f + __expf(-x2));
      v.w = 1.f / (1.f + __expf(-x3));
      *(float4*)&out[((size_t)n * PP + p) * CHC + cbase] = v;
    }
  }
}

// ---------------------------------------------------------------------------
extern "C" void kernel_launch(void* const* d_in, const int* in_sizes, int n_in,
                              void* d_out, int out_size, void* d_ws,
                              size_t ws_size, hipStream_t stream) {
  (void)in_sizes;
  (void)n_in;
  (void)out_size;
  const float* z = (const float*)d_in[0];
  const float* W6 = (const float*)d_in[1];
  const float* b6 = (const float*)d_in[2];
  const float* g6 = (const float*)d_in[3];
  const float* be6 = (const float*)d_in[4];
  const float* W7 = (const float*)d_in[5];
  const float* b7 = (const float*)d_in[6];
  const float* g7 = (const float*)d_in[7];
  const float* be7 = (const float*)d_in[8];
  const float* W8 = (const float*)d_in[9];
  const float* b8 = (const float*)d_in[10];
  float* out = (float*)d_out;
  float* hdr = (float*)d_ws;
  float* h2buf = (float*)((char*)d_ws + HDR_BYTES);

  // p-grouping: fit h2_raw (64 MB per p) into whatever workspace we have
  size_t per_p = (size_t)NB * H2C * sizeof(float);
  size_t avail = ws_size > (size_t)HDR_BYTES ? ws_size - HDR_BYTES : 0;
  int PG = (int)(avail / per_p);
  if (PG < 1) PG = 1;
  if (PG > PP) PG = PP;

  // BN1 stats (independent of h2 buffer, do once for all P)
  hipMemsetAsync(hdr + OFF_S1SUM, 0, 2048 * sizeof(float), stream);
  k1_stats1<<<dim3(NB / 512, PP), 128, 0, stream>>>(z, W6, b6, hdr);
  k1_fin<<<4, 256, 0, stream>>>(g6, be6, hdr);

  for (int p0 = 0; p0 < PP; p0 += PG) {
    int pg = (PP - p0) < PG ? (PP - p0) : PG;
    hipMemsetAsync(hdr + OFF_S2SUM, 0, 8192 * sizeof(float), stream);
    k2_gemm2<<<dim3(NB / 64, H2C / 64, pg), 256, 0, stream>>>(
        z, W6, b6, W7, b7, hdr, h2buf, p0);
    k3_stats2<<<dim3(NB / 1024, pg), 256, 0, stream>>>(h2buf, hdr, p0);
    k3_fin<<<(pg * H2C + 255) / 256, 256, 0, stream>>>(g7, be7, hdr, p0, pg);
    k4_gemm3<<<dim3(NB / 64, (CHC + 63) / 64, pg), 256, 0, stream>>>(
        h2buf, W8, b8, hdr, out, p0);
  }
}

// Round 2
// 515.044 us; speedup vs baseline: 4.9911x; 4.9911x over previous
//
#include <hip/hip_runtime.h>

#define PP 8
#define ZD 16
#define H1C 128
#define H2C 512
#define CHC 224
#define NB 32768
#define EPSV 1e-5f

// header layout in d_ws (float offsets)
#define OFF_S1SUM 0
#define OFF_S1SQ  1024
#define OFF_SC1   2048
#define OFF_SH1   3072
#define OFF_S2SUM 4096
#define OFF_S2SQ  8192
#define OFF_SC2   12288
#define OFF_SH2   16384
#define HDR_BYTES 81920

typedef __attribute__((ext_vector_type(8))) short s16x8;
typedef __attribute__((ext_vector_type(4))) short s16x4;
typedef __attribute__((ext_vector_type(4))) float f32x4;

__device__ __forceinline__ unsigned short f2bf(float f) {
  unsigned int u = __float_as_uint(f);
  unsigned int r = (u + 0x7fffu + ((u >> 16) & 1u)) >> 16;
  return (unsigned short)r;
}
__device__ __forceinline__ float bf2f(unsigned short h) {
  return __uint_as_float((unsigned int)h << 16);
}

// async global->LDS, 16B per lane; lds dest must be wave-uniform base
#define GLL16(g, l)                                                        \
  __builtin_amdgcn_global_load_lds(                                        \
      (const __attribute__((address_space(1))) unsigned int*)(g),          \
      (__attribute__((address_space(3))) unsigned int*)(l), 16, 0, 0)

// ---------------------------------------------------------------------------
// kw: convert W7, W8 to bf16 (K-contiguous [out][K] layout preserved)
__global__ __launch_bounds__(256) void kw_conv(
    const float* __restrict__ W7, const float* __restrict__ W8,
    unsigned short* __restrict__ W7b, unsigned short* __restrict__ W8b) {
  const int N7 = PP * H2C * H1C;  // 524288
  const int N8 = PP * CHC * H2C;  // 917504
  int i4 = (blockIdx.x * 256 + threadIdx.x) * 4;
  if (i4 < N7) {
    float4 v = *(const float4*)&W7[i4];
    s16x4 o;
    o[0] = (short)f2bf(v.x); o[1] = (short)f2bf(v.y);
    o[2] = (short)f2bf(v.z); o[3] = (short)f2bf(v.w);
    *(s16x4*)&W7b[i4] = o;
  } else {
    int j4 = i4 - N7;
    if (j4 < N8) {
      float4 v = *(const float4*)&W8[j4];
      s16x4 o;
      o[0] = (short)f2bf(v.x); o[1] = (short)f2bf(v.y);
      o[2] = (short)f2bf(v.z); o[3] = (short)f2bf(v.w);
      *(s16x4*)&W8b[j4] = o;
    }
  }
}

// ---------------------------------------------------------------------------
// K1: BN1 stats (fp32 h1 recompute from z, K=16)
__global__ __launch_bounds__(128) void k1_stats1(
    const float* __restrict__ z, const float* __restrict__ W6,
    const float* __restrict__ b6, float* __restrict__ hdr) {
  __shared__ float zs[512 * ZD];   // 32KB
  __shared__ float w6s[H1C * ZD];  // 8KB
  const int t = threadIdx.x;
  const int p = blockIdx.y;
  const int n0 = blockIdx.x * 512;
  for (int i = t; i < H1C * ZD; i += 128) w6s[i] = W6[(size_t)p * (H1C * ZD) + i];
  for (int i = t; i < 512 * ZD; i += 128) zs[i] = z[(size_t)n0 * ZD + i];
  __syncthreads();
  float wr_[ZD];
#pragma unroll
  for (int q = 0; q < ZD; ++q) wr_[q] = w6s[t * ZD + q];
  float bb = b6[p * H1C + t];
  float s = 0.f, sq = 0.f;
  for (int n = 0; n < 512; ++n) {
    float v = bb;
    const float4* zp = (const float4*)&zs[n * ZD];
#pragma unroll
    for (int q4 = 0; q4 < 4; ++q4) {
      float4 zv = zp[q4];
      v = fmaf(zv.x, wr_[q4 * 4 + 0], v);
      v = fmaf(zv.y, wr_[q4 * 4 + 1], v);
      v = fmaf(zv.z, wr_[q4 * 4 + 2], v);
      v = fmaf(zv.w, wr_[q4 * 4 + 3], v);
    }
    s += v;
    sq = fmaf(v, v, sq);
  }
  atomicAdd(&hdr[OFF_S1SUM + p * H1C + t], s);
  atomicAdd(&hdr[OFF_S1SQ + p * H1C + t], sq);
}

__global__ void k1_fin(const float* __restrict__ g6,
                       const float* __restrict__ be6, float* __restrict__ hdr) {
  int j = blockIdx.x * 256 + threadIdx.x;
  if (j >= PP * H1C) return;
  float mu = hdr[OFF_S1SUM + j] * (1.f / NB);
  float var = fmaxf(hdr[OFF_S1SQ + j] * (1.f / NB) - mu * mu, 0.f);
  float sc = g6[j] * rsqrtf(var + EPSV);
  hdr[OFF_SC1 + j] = sc;
  hdr[OFF_SH1 + j] = be6[j] - mu * sc;
}

// ---------------------------------------------------------------------------
// K1c: materialize h1act = relu(affine(z*W6^T)) as bf16 [p][n][128]
__global__ __launch_bounds__(256) void k1c_act1(
    const float* __restrict__ z, const float* __restrict__ W6,
    const float* __restrict__ b6, const float* __restrict__ hdr,
    unsigned short* __restrict__ h1a) {
  __shared__ float w6s[H1C * 20];  // padded to 20 for float4 reads
  __shared__ float cb[H1C], cs[H1C], ch[H1C];
  const int t = threadIdx.x;
  const int p = blockIdx.y;
  const int n0 = blockIdx.x * 128;
  for (int i = t; i < H1C * ZD; i += 256)
    w6s[(i >> 4) * 20 + (i & 15)] = W6[(size_t)p * (H1C * ZD) + i];
  if (t < H1C) {
    cb[t] = b6[p * H1C + t];
    cs[t] = hdr[OFF_SC1 + p * H1C + t];
    ch[t] = hdr[OFF_SH1 + p * H1C + t];
  }
  __syncthreads();
  const int row = t >> 1;
  const int h0 = (t & 1) * 64;
  const float* zp = z + (size_t)(n0 + row) * ZD;
  float zr[ZD];
#pragma unroll
  for (int q = 0; q < ZD; ++q) zr[q] = zp[q];
  unsigned short* op = h1a + ((size_t)p * NB + n0 + row) * H1C + h0;
  for (int hb = 0; hb < 64; hb += 8) {
    s16x8 o;
#pragma unroll
    for (int j = 0; j < 8; ++j) {
      int h = h0 + hb + j;
      float v = cb[h];
#pragma unroll
      for (int q4 = 0; q4 < 4; ++q4) {
        float4 wv = *(const float4*)&w6s[h * 20 + q4 * 4];
        v = fmaf(zr[q4 * 4 + 0], wv.x, v);
        v = fmaf(zr[q4 * 4 + 1], wv.y, v);
        v = fmaf(zr[q4 * 4 + 2], wv.z, v);
        v = fmaf(zr[q4 * 4 + 3], wv.w, v);
      }
      v = fmaxf(fmaf(v, cs[h], ch[h]), 0.f);
      o[j] = (short)f2bf(v);
    }
    *(s16x8*)(op + hb) = o;
  }
}

// ---------------------------------------------------------------------------
// K2: bf16 MFMA GEMM (M=NB, N=512, K=128) h2_raw = h1act*W7^T + b7 -> bf16
// + fused BN2 sum/sumsq. 128x128 tile, BK=64, 4 waves 2x2, m97 structure.
__global__ __launch_bounds__(256) void k2_gemm2(
    const unsigned short* __restrict__ h1a, const unsigned short* __restrict__ W7b,
    const float* __restrict__ b7, float* __restrict__ hdr,
    unsigned short* __restrict__ h2b, int p0) {
  __shared__ unsigned short Abuf[128 * 64];  // 16KB [row][k]
  __shared__ unsigned short Bbuf[128 * 64];  // 16KB [col][k]
  const int t = threadIdx.x;
  const int lane = t & 63;
  const int w = t >> 6, wr = w >> 1, wc = w & 1;
  const int pl = blockIdx.z, p = p0 + pl;
  const int n0 = blockIdx.x * 128;
  const int c0 = blockIdx.y * 128;

  const int srow = lane >> 3;
  const int ke = (lane & 7) * 8;
  const size_t abase = ((size_t)p * NB + n0) * H1C;
  const size_t bbase = ((size_t)p * H2C + c0) * H1C;

  f32x4 acc[4][4] = {};

  for (int kt = 0; kt < H1C / 64; ++kt) {
    __syncthreads();
#pragma unroll
    for (int c = 0; c < 4; ++c) {
      int row = (w * 4 + c) * 8 + srow;
      GLL16(h1a + abase + (size_t)row * H1C + kt * 64 + ke,
            (char*)Abuf + (w * 4 + c) * 1024);
      GLL16(W7b + bbase + (size_t)row * H1C + kt * 64 + ke,
            (char*)Bbuf + (w * 4 + c) * 1024);
    }
    __syncthreads();
#pragma unroll
    for (int kk = 0; kk < 2; ++kk) {
      const int klane = kk * 32 + (lane >> 4) * 8;
      s16x8 af[4], bf[4];
#pragma unroll
      for (int m = 0; m < 4; ++m)
        af[m] = *(const s16x8*)&Abuf[(wr * 64 + m * 16 + (lane & 15)) * 64 + klane];
#pragma unroll
      for (int n = 0; n < 4; ++n)
        bf[n] = *(const s16x8*)&Bbuf[(wc * 64 + n * 16 + (lane & 15)) * 64 + klane];
#pragma unroll
      for (int m = 0; m < 4; ++m)
#pragma unroll
        for (int n = 0; n < 4; ++n)
          acc[m][n] = __builtin_amdgcn_mfma_f32_16x16x32_bf16(af[m], bf[n],
                                                              acc[m][n], 0, 0, 0);
    }
  }

  // epilogue: +b7, round bf16, store, fused BN2 partial stats
#pragma unroll
  for (int n = 0; n < 4; ++n) {
    const int col = c0 + wc * 64 + n * 16 + (lane & 15);
    const float bias = b7[p * H2C + col];
    float s = 0.f, q = 0.f;
#pragma unroll
    for (int m = 0; m < 4; ++m) {
      const int rowb = n0 + wr * 64 + m * 16 + (lane >> 4) * 4;
#pragma unroll
      for (int r = 0; r < 4; ++r) {
        float v = acc[m][n][r] + bias;
        unsigned short hb = f2bf(v);
        h2b[((size_t)pl * NB + rowb + r) * H2C + col] = hb;
        float vf = bf2f(hb);
        s += vf;
        q = fmaf(vf, vf, q);
      }
    }
    s += __shfl_xor(s, 16); q += __shfl_xor(q, 16);
    s += __shfl_xor(s, 32); q += __shfl_xor(q, 32);
    if ((lane >> 4) == 0) {
      atomicAdd(&hdr[OFF_S2SUM + p * H2C + col], s);
      atomicAdd(&hdr[OFF_S2SQ + p * H2C + col], q);
    }
  }
}

__global__ void k3_fin(const float* __restrict__ g7,
                       const float* __restrict__ be7, float* __restrict__ hdr,
                       int p0, int pg) {
  int idx = blockIdx.x * 256 + threadIdx.x;
  if (idx >= pg * H2C) return;
  int row = p0 * H2C + idx;
  float mu = hdr[OFF_S2SUM + row] * (1.f / NB);
  float var = fmaxf(hdr[OFF_S2SQ + row] * (1.f / NB) - mu * mu, 0.f);
  float sc = g7[row] * rsqrtf(var + EPSV);
  hdr[OFF_SC2 + row] = sc;
  hdr[OFF_SH2 + row] = be7[row] - mu * sc;
}

// ---------------------------------------------------------------------------
// K3b: in-place h2 <- relu(affine2(h2)) as bf16 (elementwise, vectorized x8)
__global__ __launch_bounds__(256) void k3b_act2(unsigned short* __restrict__ h2,
                                                const float* __restrict__ hdr,
                                                int p0) {
  const size_t i8 = ((size_t)blockIdx.x * 256 + threadIdx.x) * 8;
  const int col = (int)(i8 & (H2C - 1));
  const int pl = (int)(i8 / ((size_t)NB * H2C));
  const int p = p0 + pl;
  const float* scp = hdr + OFF_SC2 + p * H2C + col;
  const float* shp = hdr + OFF_SH2 + p * H2C + col;
  float4 sc0 = *(const float4*)scp, sc1 = *(const float4*)(scp + 4);
  float4 sh0 = *(const float4*)shp, sh1 = *(const float4*)(shp + 4);
  s16x8 v = *(s16x8*)(h2 + i8);
  s16x8 o;
  o[0] = (short)f2bf(fmaxf(fmaf(bf2f((unsigned short)v[0]), sc0.x, sh0.x), 0.f));
  o[1] = (short)f2bf(fmaxf(fmaf(bf2f((unsigned short)v[1]), sc0.y, sh0.y), 0.f));
  o[2] = (short)f2bf(fmaxf(fmaf(bf2f((unsigned short)v[2]), sc0.z, sh0.z), 0.f));
  o[3] = (short)f2bf(fmaxf(fmaf(bf2f((unsigned short)v[3]), sc0.w, sh0.w), 0.f));
  o[4] = (short)f2bf(fmaxf(fmaf(bf2f((unsigned short)v[4]), sc1.x, sh1.x), 0.f));
  o[5] = (short)f2bf(fmaxf(fmaf(bf2f((unsigned short)v[5]), sc1.y, sh1.y), 0.f));
  o[6] = (short)f2bf(fmaxf(fmaf(bf2f((unsigned short)v[6]), sc1.z, sh1.z), 0.f));
  o[7] = (short)f2bf(fmaxf(fmaf(bf2f((unsigned short)v[7]), sc1.w, sh1.w), 0.f));
  *(s16x8*)(h2 + i8) = o;
}

// ---------------------------------------------------------------------------
// K4: bf16 MFMA GEMM (M=NB, N=224 padded to 2x128, K=512) + bias + sigmoid
// + transposed fp32 store out[n][p][c].
__global__ __launch_bounds__(256) void k4_gemm3(
    const unsigned short* __restrict__ h2a, const unsigned short* __restrict__ W8b,
    const float* __restrict__ b8, float* __restrict__ out, int p0) {
  __shared__ unsigned short Abuf[128 * 64];
  __shared__ unsigned short Bbuf[128 * 64];
  const int t = threadIdx.x;
  const int lane = t & 63;
  const int w = t >> 6, wr = w >> 1, wc = w & 1;
  const int pl = blockIdx.z, p = p0 + pl;
  const int n0 = blockIdx.x * 128;
  const int c0 = blockIdx.y * 128;

  const int srow = lane >> 3;
  const int ke = (lane & 7) * 8;
  const size_t abase = ((size_t)pl * NB + n0) * H2C;

  f32x4 acc[4][4] = {};

  for (int kt = 0; kt < H2C / 64; ++kt) {
    __syncthreads();
#pragma unroll
    for (int c = 0; c < 4; ++c) {
      int row = (w * 4 + c) * 8 + srow;
      GLL16(h2a + abase + (size_t)row * H2C + kt * 64 + ke,
            (char*)Abuf + (w * 4 + c) * 1024);
      int crow = c0 + row;
      if (crow > CHC - 1) crow = CHC - 1;  // clamp: cols >=224 masked at write
      GLL16(W8b + ((size_t)p * CHC + crow) * H2C + kt * 64 + ke,
            (char*)Bbuf + (w * 4 + c) * 1024);
    }
    __syncthreads();
#pragma unroll
    for (int kk = 0; kk < 2; ++kk) {
      const int klane = kk * 32 + (lane >> 4) * 8;
      s16x8 af[4], bf[4];
#pragma unroll
      for (int m = 0; m < 4; ++m)
        af[m] = *(const s16x8*)&Abuf[(wr * 64 + m * 16 + (lane & 15)) * 64 + klane];
#pragma unroll
      for (int n = 0; n < 4; ++n)
        bf[n] = *(const s16x8*)&Bbuf[(wc * 64 + n * 16 + (lane & 15)) * 64 + klane];
#pragma unroll
      for (int m = 0; m < 4; ++m)
#pragma unroll
        for (int n = 0; n < 4; ++n)
          acc[m][n] = __builtin_amdgcn_mfma_f32_16x16x32_bf16(af[m], bf[n],
                                                              acc[m][n], 0, 0, 0);
    }
  }

#pragma unroll
  for (int n = 0; n < 4; ++n) {
    const int col = c0 + wc * 64 + n * 16 + (lane & 15);
    if (col < CHC) {
      const float bias = b8[p * CHC + col];
#pragma unroll
      for (int m = 0; m < 4; ++m) {
        const int rowb = n0 + wr * 64 + m * 16 + (lane >> 4) * 4;
#pragma unroll
        for (int r = 0; r < 4; ++r) {
          float x = acc[m][n][r] + bias;
          out[((size_t)(rowb + r) * PP + p) * CHC + col] = 1.f / (1.f + __expf(-x));
        }
      }
    }
  }
}

// ---------------------------------------------------------------------------
extern "C" void kernel_launch(void* const* d_in, const int* in_sizes, int n_in,
                              void* d_out, int out_size, void* d_ws,
                              size_t ws_size, hipStream_t stream) {
  (void)in_sizes; (void)n_in; (void)out_size;
  const float* z   = (const float*)d_in[0];
  const float* W6  = (const float*)d_in[1];
  const float* b6  = (const float*)d_in[2];
  const float* g6  = (const float*)d_in[3];
  const float* be6 = (const float*)d_in[4];
  const float* W7  = (const float*)d_in[5];
  const float* b7  = (const float*)d_in[6];
  const float* g7  = (const float*)d_in[7];
  const float* be7 = (const float*)d_in[8];
  const float* W8  = (const float*)d_in[9];
  const float* b8  = (const float*)d_in[10];
  float* out = (float*)d_out;
  float* hdr = (float*)d_ws;
  unsigned short* W7b = (unsigned short*)((char*)d_ws + HDR_BYTES);
  unsigned short* W8b = W7b + (size_t)PP * H2C * H1C;
  unsigned short* h1a = W8b + (size_t)PP * CHC * H2C;
  unsigned short* h2b = h1a + (size_t)PP * NB * H1C;

  size_t fixed = HDR_BYTES + 2 * ((size_t)PP * H2C * H1C + (size_t)PP * CHC * H2C +
                                  (size_t)PP * NB * H1C);
  size_t per_p = (size_t)NB * H2C * 2;
  size_t avail = ws_size > fixed ? ws_size - fixed : 0;
  int PG = (int)(avail / per_p);
  if (PG < 1) PG = 1;
  if (PG > PP) PG = PP;

  hipMemsetAsync(hdr + OFF_S1SUM, 0, 2048 * sizeof(float), stream);
  kw_conv<<<1408, 256, 0, stream>>>(W7, W8, W7b, W8b);
  k1_stats1<<<dim3(NB / 512, PP), 128, 0, stream>>>(z, W6, b6, hdr);
  k1_fin<<<4, 256, 0, stream>>>(g6, be6, hdr);
  k1c_act1<<<dim3(NB / 128, PP), 256, 0, stream>>>(z, W6, b6, hdr, h1a);

  for (int p0 = 0; p0 < PP; p0 += PG) {
    int pg = (PP - p0 < PG) ? PP - p0 : PG;
    hipMemsetAsync(hdr + OFF_S2SUM, 0, 8192 * sizeof(float), stream);
    k2_gemm2<<<dim3(NB / 128, H2C / 128, pg), 256, 0, stream>>>(h1a, W7b, b7,
                                                                hdr, h2b, p0);
    k3_fin<<<(pg * H2C + 255) / 256, 256, 0, stream>>>(g7, be7, hdr, p0, pg);
    k3b_act2<<<dim3(pg * 8192), 256, 0, stream>>>(h2b, hdr, p0);
    k4_gemm3<<<dim3(NB / 128, 2, pg), 256, 0, stream>>>(h2b, W8b, b8, out, p0);
  }
}

// Round 3
// 419.582 us; speedup vs baseline: 6.1267x; 1.2275x over previous
//
#include <hip/hip_runtime.h>

#define PP 8
#define ZD 16
#define H1C 128
#define H2C 512
#define CHC 224
#define NB 32768
#define EPSV 1e-5f

// header layout in d_ws (float offsets)
#define OFF_S1SUM 0
#define OFF_S1SQ  1024
#define OFF_SC1   2048
#define OFF_SH1   3072
#define OFF_S2SUM 4096
#define OFF_S2SQ  8192
#define OFF_SCSH2 12288  // interleaved (sc,sh) pairs, 2*4096 floats -> ends at 20480
#define HDR_BYTES 81920

typedef __attribute__((ext_vector_type(8))) short s16x8;
typedef __attribute__((ext_vector_type(4))) float f32x4;

__device__ __forceinline__ unsigned short f2bf(float f) {
  unsigned int u = __float_as_uint(f);
  unsigned int r = (u + 0x7fffu + ((u >> 16) & 1u)) >> 16;
  return (unsigned short)r;
}
__device__ __forceinline__ float bf2f(unsigned short h) {
  return __uint_as_float((unsigned int)h << 16);
}

// async global->LDS, 16B per lane; lds dest is wave-uniform base + lane*16
#define GLL16(g, l)                                                        \
  __builtin_amdgcn_global_load_lds(                                        \
      (const __attribute__((address_space(1))) unsigned int*)(g),          \
      (__attribute__((address_space(3))) unsigned int*)(l), 16, 0, 0)

// ---------------------------------------------------------------------------
// kw: convert W7 -> W7b (slot-swizzled by c&7 within each 64-k chunk) and
// W8 -> W8b (padded to 256 rows/p, zero pad, slot-swizzled by c&7).
// Swizzle: storage slot s holds logical slot s^(c&7); 16B (8 bf16) granules.
__global__ __launch_bounds__(256) void kw_conv(
    const float* __restrict__ W7, const float* __restrict__ W8,
    unsigned short* __restrict__ W7b, unsigned short* __restrict__ W8b) {
  const int N7 = PP * H2C * H1C;   // 524288
  const int N8P = PP * 256 * H2C;  // 1048576 (dst space)
  int i8 = (blockIdx.x * 256 + threadIdx.x) * 8;
  if (i8 < N7) {
    // src-space walk; 8 consecutive logical k share a slot
    int k = i8 & (H1C - 1);
    int c = (i8 >> 7) & (H2C - 1);
    int base = i8 - k;
    int kd = (k & ~63) + ((((k >> 3) & 7) ^ (c & 7)) << 3);
    float4 v0 = *(const float4*)&W7[i8];
    float4 v1 = *(const float4*)&W7[i8 + 4];
    s16x8 o;
    o[0] = (short)f2bf(v0.x); o[1] = (short)f2bf(v0.y);
    o[2] = (short)f2bf(v0.z); o[3] = (short)f2bf(v0.w);
    o[4] = (short)f2bf(v1.x); o[5] = (short)f2bf(v1.y);
    o[6] = (short)f2bf(v1.z); o[7] = (short)f2bf(v1.w);
    *(s16x8*)&W7b[base + kd] = o;
  } else {
    int d = i8 - N7;  // dst-space walk over [p][256][512]
    if (d < N8P) {
      int ks = d & (H2C - 1);
      int c = (d >> 9) & 255;
      int p = d >> 17;
      s16x8 o;
      if (c < CHC) {
        // logical k whose data lives at storage position ks
        int kl = (ks & ~63) + ((((ks >> 3) & 7) ^ (c & 7)) << 3) + (ks & 7);
        const float* src = &W8[((size_t)p * CHC + c) * H2C + kl];
        float4 v0 = *(const float4*)src;
        float4 v1 = *(const float4*)(src + 4);
        o[0] = (short)f2bf(v0.x); o[1] = (short)f2bf(v0.y);
        o[2] = (short)f2bf(v0.z); o[3] = (short)f2bf(v0.w);
        o[4] = (short)f2bf(v1.x); o[5] = (short)f2bf(v1.y);
        o[6] = (short)f2bf(v1.z); o[7] = (short)f2bf(v1.w);
      } else {
        o = (s16x8)0;
      }
      *(s16x8*)&W8b[d] = o;
    }
  }
}

// ---------------------------------------------------------------------------
// K1: BN1 stats (fp32 h1 recompute from z, K=16)
__global__ __launch_bounds__(128) void k1_stats1(
    const float* __restrict__ z, const float* __restrict__ W6,
    const float* __restrict__ b6, float* __restrict__ hdr) {
  __shared__ float zs[512 * ZD];
  __shared__ float w6s[H1C * ZD];
  const int t = threadIdx.x;
  const int p = blockIdx.y;
  const int n0 = blockIdx.x * 512;
  for (int i = t; i < H1C * ZD; i += 128) w6s[i] = W6[(size_t)p * (H1C * ZD) + i];
  for (int i = t; i < 512 * ZD; i += 128) zs[i] = z[(size_t)n0 * ZD + i];
  __syncthreads();
  float wr_[ZD];
#pragma unroll
  for (int q = 0; q < ZD; ++q) wr_[q] = w6s[t * ZD + q];
  float bb = b6[p * H1C + t];
  float s = 0.f, sq = 0.f;
  for (int n = 0; n < 512; ++n) {
    float v = bb;
    const float4* zp = (const float4*)&zs[n * ZD];
#pragma unroll
    for (int q4 = 0; q4 < 4; ++q4) {
      float4 zv = zp[q4];
      v = fmaf(zv.x, wr_[q4 * 4 + 0], v);
      v = fmaf(zv.y, wr_[q4 * 4 + 1], v);
      v = fmaf(zv.z, wr_[q4 * 4 + 2], v);
      v = fmaf(zv.w, wr_[q4 * 4 + 3], v);
    }
    s += v;
    sq = fmaf(v, v, sq);
  }
  atomicAdd(&hdr[OFF_S1SUM + p * H1C + t], s);
  atomicAdd(&hdr[OFF_S1SQ + p * H1C + t], sq);
}

__global__ void k1_fin(const float* __restrict__ g6,
                       const float* __restrict__ be6, float* __restrict__ hdr) {
  int j = blockIdx.x * 256 + threadIdx.x;
  if (j >= PP * H1C) return;
  float mu = hdr[OFF_S1SUM + j] * (1.f / NB);
  float var = fmaxf(hdr[OFF_S1SQ + j] * (1.f / NB) - mu * mu, 0.f);
  float sc = g6[j] * rsqrtf(var + EPSV);
  hdr[OFF_SC1 + j] = sc;
  hdr[OFF_SH1 + j] = be6[j] - mu * sc;
}

// ---------------------------------------------------------------------------
// K1c: h1act = relu(affine(z*W6^T)) bf16 [p][n][128], slot-swizzled by n&7
__global__ __launch_bounds__(256) void k1c_act1(
    const float* __restrict__ z, const float* __restrict__ W6,
    const float* __restrict__ b6, const float* __restrict__ hdr,
    unsigned short* __restrict__ h1a) {
  __shared__ float w6s[H1C * 20];
  __shared__ float cb[H1C], cs[H1C], ch[H1C];
  const int t = threadIdx.x;
  const int p = blockIdx.y;
  const int n0 = blockIdx.x * 128;
  for (int i = t; i < H1C * ZD; i += 256)
    w6s[(i >> 4) * 20 + (i & 15)] = W6[(size_t)p * (H1C * ZD) + i];
  if (t < H1C) {
    cb[t] = b6[p * H1C + t];
    cs[t] = hdr[OFF_SC1 + p * H1C + t];
    ch[t] = hdr[OFF_SH1 + p * H1C + t];
  }
  __syncthreads();
  const int row = t >> 1;
  const int n = n0 + row;
  const int h0 = (t & 1) * 64;
  const float* zp = z + (size_t)n * ZD;
  float zr[ZD];
#pragma unroll
  for (int q = 0; q < ZD; ++q) zr[q] = zp[q];
  unsigned short* rowp = h1a + ((size_t)p * NB + n) * H1C;
  for (int hb = 0; hb < 64; hb += 8) {
    s16x8 o;
#pragma unroll
    for (int j = 0; j < 8; ++j) {
      int h = h0 + hb + j;
      float v = cb[h];
#pragma unroll
      for (int q4 = 0; q4 < 4; ++q4) {
        float4 wv = *(const float4*)&w6s[h * 20 + q4 * 4];
        v = fmaf(zr[q4 * 4 + 0], wv.x, v);
        v = fmaf(zr[q4 * 4 + 1], wv.y, v);
        v = fmaf(zr[q4 * 4 + 2], wv.z, v);
        v = fmaf(zr[q4 * 4 + 3], wv.w, v);
      }
      v = fmaxf(fmaf(v, cs[h], ch[h]), 0.f);
      o[j] = (short)f2bf(v);
    }
    int hbase = h0 + hb;  // group of 8, one slot
    int kd = (hbase & ~63) + ((((hbase >> 3) & 7) ^ (n & 7)) << 3);
    *(s16x8*)(rowp + kd) = o;
  }
}

// ---------------------------------------------------------------------------
// K2: bf16 MFMA GEMM (M=NB, N=512, K=128), fused bias + BN2 stats epilogue.
// Operands pre-swizzled in global; GLL linear; XOR on fragment reads.
__global__ __launch_bounds__(256) void k2_gemm2(
    const unsigned short* __restrict__ h1a, const unsigned short* __restrict__ W7b,
    const float* __restrict__ b7, float* __restrict__ hdr,
    unsigned short* __restrict__ h2b, int p0) {
  __shared__ unsigned short Abuf[128 * 64];
  __shared__ unsigned short Bbuf[128 * 64];
  const int t = threadIdx.x;
  const int lane = t & 63;
  const int w = t >> 6, wr = w >> 1, wc = w & 1;
  const int pl = blockIdx.z, p = p0 + pl;
  const int n0 = blockIdx.x * 128;
  const int c0 = blockIdx.y * 128;

  const int srow = lane >> 3;
  const int ke = (lane & 7) * 8;
  const size_t abase = ((size_t)p * NB + n0) * H1C;
  const size_t bbase = ((size_t)p * H2C + c0) * H1C;

  f32x4 acc[4][4] = {};

  for (int kt = 0; kt < H1C / 64; ++kt) {
    __syncthreads();
#pragma unroll
    for (int c = 0; c < 4; ++c) {
      int row = (w * 4 + c) * 8 + srow;
      GLL16(h1a + abase + (size_t)row * H1C + kt * 64 + ke,
            (char*)Abuf + (w * 4 + c) * 1024);
      GLL16(W7b + bbase + (size_t)row * H1C + kt * 64 + ke,
            (char*)Bbuf + (w * 4 + c) * 1024);
    }
    __syncthreads();
    const int sw = lane & 7;
#pragma unroll
    for (int kk = 0; kk < 2; ++kk) {
      const int sl = kk * 4 + (lane >> 4);
      s16x8 af[4], bfv[4];
#pragma unroll
      for (int m = 0; m < 4; ++m)
        af[m] = *(const s16x8*)&Abuf[(wr * 64 + m * 16 + (lane & 15)) * 64 +
                                     ((sl ^ sw) << 3)];
#pragma unroll
      for (int n = 0; n < 4; ++n)
        bfv[n] = *(const s16x8*)&Bbuf[(wc * 64 + n * 16 + (lane & 15)) * 64 +
                                      ((sl ^ sw) << 3)];
#pragma unroll
      for (int m = 0; m < 4; ++m)
#pragma unroll
        for (int n = 0; n < 4; ++n)
          acc[m][n] = __builtin_amdgcn_mfma_f32_16x16x32_bf16(af[m], bfv[n],
                                                              acc[m][n], 0, 0, 0);
    }
  }

#pragma unroll
  for (int n = 0; n < 4; ++n) {
    const int col = c0 + wc * 64 + n * 16 + (lane & 15);
    const float bias = b7[p * H2C + col];
    float s = 0.f, q = 0.f;
#pragma unroll
    for (int m = 0; m < 4; ++m) {
      const int rowb = n0 + wr * 64 + m * 16 + (lane >> 4) * 4;
#pragma unroll
      for (int r = 0; r < 4; ++r) {
        float v = acc[m][n][r] + bias;
        unsigned short hb = f2bf(v);
        h2b[((size_t)pl * NB + rowb + r) * H2C + col] = hb;
        float vf = bf2f(hb);
        s += vf;
        q = fmaf(vf, vf, q);
      }
    }
    s += __shfl_xor(s, 16); q += __shfl_xor(q, 16);
    s += __shfl_xor(s, 32); q += __shfl_xor(q, 32);
    if ((lane >> 4) == 0) {
      atomicAdd(&hdr[OFF_S2SUM + p * H2C + col], s);
      atomicAdd(&hdr[OFF_S2SQ + p * H2C + col], q);
    }
  }
}

// K3fin: BN2 affine params, interleaved (sc,sh) pairs for k4's staging table
__global__ void k3_fin(const float* __restrict__ g7,
                       const float* __restrict__ be7, float* __restrict__ hdr,
                       int p0, int pg) {
  int idx = blockIdx.x * 256 + threadIdx.x;
  if (idx >= pg * H2C) return;
  int row = p0 * H2C + idx;
  float mu = hdr[OFF_S2SUM + row] * (1.f / NB);
  float var = fmaxf(hdr[OFF_S2SQ + row] * (1.f / NB) - mu * mu, 0.f);
  float sc = g7[row] * rsqrtf(var + EPSV);
  hdr[OFF_SCSH2 + 2 * row] = sc;
  hdr[OFF_SCSH2 + 2 * row + 1] = be7[row] - mu * sc;
}

// ---------------------------------------------------------------------------
// K4: bf16 MFMA GEMM (M=NB, N=256 incl. pad, K=512), 128x256 tile.
// A: reg-staged from linear h2b with fused relu(sc*v+sh), XOR-swizzled ds_write.
// B: GLL from pre-swizzled zero-padded W8b. Epilogue: bias+sigmoid+transposed store.
__global__ __launch_bounds__(256, 2) void k4_gemm3(
    const unsigned short* __restrict__ h2b, const unsigned short* __restrict__ W8b,
    const float* __restrict__ b8, const float* __restrict__ hdr,
    float* __restrict__ out, int p0) {
  __shared__ unsigned short Abuf[128 * 64];  // 16KB, swizzled by row&7
  __shared__ unsigned short Bbuf[256 * 64];  // 32KB, swizzled via global
  __shared__ float scsh[2 * H2C];            // 4KB (sc,sh) pairs
  const int t = threadIdx.x;
  const int lane = t & 63;
  const int w = t >> 6, wr = w >> 1, wc = w & 1;
  const int pl = blockIdx.z, p = p0 + pl;
  const int n0 = blockIdx.x * 128;

  *(float4*)&scsh[t * 4] = *(const float4*)&hdr[OFF_SCSH2 + p * (2 * H2C) + t * 4];

  const int r = t >> 1;        // A staging row
  const int sb = (t & 1) * 4;  // slot base {0,4}
  const unsigned short* arow =
      h2b + ((size_t)pl * NB + n0 + r) * H2C + sb * 8;
  const int qrow = lane >> 3, qsl = lane & 7;

  f32x4 acc[4][8] = {};

  for (int kt = 0; kt < H2C / 64; ++kt) {
    __syncthreads();  // prev frag reads done; scsh visible on kt==0
    s16x8 raw[4];
#pragma unroll
    for (int j = 0; j < 4; ++j) raw[j] = *(const s16x8*)(arow + kt * 64 + j * 8);
#pragma unroll
    for (int c = 0; c < 8; ++c) {
      int qq = w * 8 + c;
      GLL16(W8b + ((size_t)p * 256 + qq * 8 + qrow) * H2C + kt * 64 + qsl * 8,
            (char*)Bbuf + qq * 1024);
    }
#pragma unroll
    for (int j = 0; j < 4; ++j) {
      int kb = kt * 64 + sb * 8 + j * 8;
      f32x4 s0 = *(const f32x4*)&scsh[2 * kb];
      f32x4 s1 = *(const f32x4*)&scsh[2 * kb + 4];
      f32x4 s2 = *(const f32x4*)&scsh[2 * kb + 8];
      f32x4 s3 = *(const f32x4*)&scsh[2 * kb + 12];
      s16x8 o;
      o[0] = (short)f2bf(fmaxf(fmaf(bf2f((unsigned short)raw[j][0]), s0[0], s0[1]), 0.f));
      o[1] = (short)f2bf(fmaxf(fmaf(bf2f((unsigned short)raw[j][1]), s0[2], s0[3]), 0.f));
      o[2] = (short)f2bf(fmaxf(fmaf(bf2f((unsigned short)raw[j][2]), s1[0], s1[1]), 0.f));
      o[3] = (short)f2bf(fmaxf(fmaf(bf2f((unsigned short)raw[j][3]), s1[2], s1[3]), 0.f));
      o[4] = (short)f2bf(fmaxf(fmaf(bf2f((unsigned short)raw[j][4]), s2[0], s2[1]), 0.f));
      o[5] = (short)f2bf(fmaxf(fmaf(bf2f((unsigned short)raw[j][5]), s2[2], s2[3]), 0.f));
      o[6] = (short)f2bf(fmaxf(fmaf(bf2f((unsigned short)raw[j][6]), s3[0], s3[1]), 0.f));
      o[7] = (short)f2bf(fmaxf(fmaf(bf2f((unsigned short)raw[j][7]), s3[2], s3[3]), 0.f));
      int slot = (sb + j) ^ (r & 7);
      *(s16x8*)((char*)Abuf + r * 128 + slot * 16) = o;
    }
    __syncthreads();
    const int sw = lane & 7;
#pragma unroll
    for (int kk = 0; kk < 2; ++kk) {
      const int sl = kk * 4 + (lane >> 4);
      s16x8 af[4], bfv[8];
#pragma unroll
      for (int m = 0; m < 4; ++m)
        af[m] = *(const s16x8*)&Abuf[(wr * 64 + m * 16 + (lane & 15)) * 64 +
                                     ((sl ^ sw) << 3)];
#pragma unroll
      for (int n = 0; n < 8; ++n)
        bfv[n] = *(const s16x8*)&Bbuf[(wc * 128 + n * 16 + (lane & 15)) * 64 +
                                      ((sl ^ sw) << 3)];
#pragma unroll
      for (int m = 0; m < 4; ++m)
#pragma unroll
        for (int n = 0; n < 8; ++n)
          acc[m][n] = __builtin_amdgcn_mfma_f32_16x16x32_bf16(af[m], bfv[n],
                                                              acc[m][n], 0, 0, 0);
    }
  }

#pragma unroll
  for (int n = 0; n < 8; ++n) {
    const int col = wc * 128 + n * 16 + (lane & 15);
    if (col < CHC) {
      const float bias = b8[p * CHC + col];
#pragma unroll
      for (int m = 0; m < 4; ++m) {
        const int rowb = n0 + wr * 64 + m * 16 + (lane >> 4) * 4;
#pragma unroll
        for (int rr = 0; rr < 4; ++rr) {
          float x = acc[m][n][rr] + bias;
          out[((size_t)(rowb + rr) * PP + p) * CHC + col] = 1.f / (1.f + __expf(-x));
        }
      }
    }
  }
}

// ---------------------------------------------------------------------------
extern "C" void kernel_launch(void* const* d_in, const int* in_sizes, int n_in,
                              void* d_out, int out_size, void* d_ws,
                              size_t ws_size, hipStream_t stream) {
  (void)in_sizes; (void)n_in; (void)out_size;
  const float* z   = (const float*)d_in[0];
  const float* W6  = (const float*)d_in[1];
  const float* b6  = (const float*)d_in[2];
  const float* g6  = (const float*)d_in[3];
  const float* be6 = (const float*)d_in[4];
  const float* W7  = (const float*)d_in[5];
  const float* b7  = (const float*)d_in[6];
  const float* g7  = (const float*)d_in[7];
  const float* be7 = (const float*)d_in[8];
  const float* W8  = (const float*)d_in[9];
  const float* b8  = (const float*)d_in[10];
  float* out = (float*)d_out;
  float* hdr = (float*)d_ws;
  unsigned short* W7b = (unsigned short*)((char*)d_ws + HDR_BYTES);
  unsigned short* W8b = W7b + (size_t)PP * H2C * H1C;
  unsigned short* h1a = W8b + (size_t)PP * 256 * H2C;
  unsigned short* h2b = h1a + (size_t)PP * NB * H1C;

  size_t fixed = HDR_BYTES + 2 * ((size_t)PP * H2C * H1C + (size_t)PP * 256 * H2C +
                                  (size_t)PP * NB * H1C);
  size_t per_p = (size_t)NB * H2C * 2;
  size_t avail = ws_size > fixed ? ws_size - fixed : 0;
  int PG = (int)(avail / per_p);
  if (PG < 1) PG = 1;
  if (PG > PP) PG = PP;

  hipMemsetAsync(hdr + OFF_S1SUM, 0, 2048 * sizeof(float), stream);
  kw_conv<<<768, 256, 0, stream>>>(W7, W8, W7b, W8b);
  k1_stats1<<<dim3(NB / 512, PP), 128, 0, stream>>>(z, W6, b6, hdr);
  k1_fin<<<4, 256, 0, stream>>>(g6, be6, hdr);
  k1c_act1<<<dim3(NB / 128, PP), 256, 0, stream>>>(z, W6, b6, hdr, h1a);

  for (int p0 = 0; p0 < PP; p0 += PG) {
    int pg = (PP - p0 < PG) ? PP - p0 : PG;
    hipMemsetAsync(hdr + OFF_S2SUM, 0, 8192 * sizeof(float), stream);
    k2_gemm2<<<dim3(NB / 128, H2C / 128, pg), 256, 0, stream>>>(h1a, W7b, b7,
                                                                hdr, h2b, p0);
    k3_fin<<<(pg * H2C + 255) / 256, 256, 0, stream>>>(g7, be7, hdr, p0, pg);
    k4_gemm3<<<dim3(NB / 128, 1, pg), 256, 0, stream>>>(h2b, W8b, b8, hdr, out,
                                                        p0);
  }
}